// Round 10
// baseline (842.676 us; speedup 1.0000x reference)
//
#include <hip/hip_runtime.h>

#define EMBD 300
#define NSTEP 300
#define HID 512
#define G4 2048
#define TPB 256
#define NWG 32

#define TS2 15              // steps per phase-1 step-group
#define NSG 20              // step groups (20*15 = 300)
#define NRG 8               // row groups (8*256 = 2048 rows)

#define SENTINEL 0xFFC00000u   // quiet NaN: h values are always finite

// ws float layout:
//   [0 .. 614400)      : X_proj [300][2048]
//   [614400 .. +154112): HSEQ [301][512]  (h state before each step)
#define XP_SZ    (NSTEP * G4)
#define HSEQ_OFF XP_SZ

__device__ __forceinline__ float fsig(float x) { return 1.0f / (1.0f + __expf(-x)); }
__device__ __forceinline__ float ftanh(float x) {
    x = fminf(15.0f, fmaxf(-15.0f, x));
    float t = __expf(2.0f * x);
    return (t - 1.0f) / (t + 1.0f);
}

// Phase 1: X_proj[t][r] = b_ih[r]+b_hh[r] + sum_e W_ih[r][e]*emb[x[t]][e]
// Grid (NRG, NSG). rowg==0 blocks sentinel-clear HSEQ rows t0+1..t0+15;
// (0,0) also copies h0 into HSEQ[0]. Re-done every call -> replay-safe.
__global__ __launch_bounds__(TPB) void xproj_init_kernel(
    const int* __restrict__ x, const float* __restrict__ h0,
    const float* __restrict__ emb, const float* __restrict__ W_ih,
    const float* __restrict__ b_ih, const float* __restrict__ b_bb,
    float* __restrict__ ws) {
    const int rowg = blockIdx.x;      // 0..7
    const int sg   = blockIdx.y;      // 0..19
    const int tid  = threadIdx.x;
    const int t0   = sg * TS2;
    const int r    = rowg * TPB + tid;

    float* hseq = ws + HSEQ_OFF;

    if (rowg == 0) {
        unsigned* hs = (unsigned*)(hseq + (size_t)(t0 + 1) * HID);
        for (int i = tid; i < TS2 * HID; i += TPB) hs[i] = SENTINEL;
        if (sg == 0) {
            for (int i = tid; i < HID; i += TPB) hseq[i] = h0[i];
        }
    }

    __shared__ float e_lds[TS2][EMBD];
    for (int tt = 0; tt < TS2; ++tt) {
        const float* er = emb + (long long)x[t0 + tt] * EMBD;
        for (int i = tid; i < EMBD; i += TPB) e_lds[tt][i] = er[i];
    }
    __syncthreads();

    float acc[TS2];
    const float bsum = b_ih[r] + b_bb[r];
    #pragma unroll
    for (int tt = 0; tt < TS2; ++tt) acc[tt] = bsum;

    const float* wrow = W_ih + (size_t)r * EMBD;
    for (int e = 0; e < EMBD; e += 4) {
        const float4 w4 = *(const float4*)(wrow + e);
        #pragma unroll
        for (int tt = 0; tt < TS2; ++tt) {
            acc[tt] = fmaf(w4.x, e_lds[tt][e],     acc[tt]);
            acc[tt] = fmaf(w4.y, e_lds[tt][e + 1], acc[tt]);
            acc[tt] = fmaf(w4.z, e_lds[tt][e + 2], acc[tt]);
            acc[tt] = fmaf(w4.w, e_lds[tt][e + 3], acc[tt]);
        }
    }
    #pragma unroll
    for (int tt = 0; tt < TS2; ++tt)
        ws[(size_t)(t0 + tt) * G4 + r] = acc[tt];
}

// Phase 2: R8 exchange structure + W_hh pinned in AGPRs.
// 32 WGs x 256 threads, 1 WG/CU, 1 wave/SIMD -> 512-reg unified VGPR/AGPR
// budget per thread. The 128 weights/thread are written ONCE into "a"-class
// registers (v_accvgpr_write_b32) and re-read each step with volatile
// v_accvgpr_read_b32 — the compiler cannot sink these to L2 reloads (the
// R1..R8 counter evidence: VGPR_Count 52-96 with 64-128 declared weights =
// W_hh silently re-streamed from L2 every step, ~850ns serial per step).
// Dot loop is k-outer/gate-inner: 8 ds_read_b128 per thread (h4 shared by
// all 4 gates). Exchange: per-thread 8B slot poll with relaxed agent atomics
// + s_sleep backoff; publish 4B per hidx; double-buffered LDS; single
// __syncthreads per step (race-free: fill@s+2 ordered after reads@s via
// own-publish -> foreign-detect chain; distance-1 uses the other buffer).
__global__ __launch_bounds__(TPB, 1) void lstm_scan_kernel(
    const float* __restrict__ c0, const float* __restrict__ W_hh,
    const float* __restrict__ fc_w, const float* __restrict__ fc_b,
    float* __restrict__ ws, float* __restrict__ out) {
    const int tid  = threadIdx.x;
    const int wg   = blockIdx.x;
    const int v    = tid >> 6;     // wave id
    const int lane = tid & 63;
    const int g    = lane >> 4;    // group within wave
    const int li   = lane & 15;    // lane within group (column split)
    const int hidx = wg * 16 + v * 4 + g;

    float* hseq     = ws + HSEQ_OFF;        // [301][512]
    const float* xp = ws;                   // [300][2048]

    __shared__ __align__(16) float h_lds[2][576];  // idx i -> i + 4*(i>>5)
    __shared__ float red[256];

    // Load W_hh slice and park it in AGPRs (one-time).
    float wa[4][32];
    #pragma unroll
    for (int gate = 0; gate < 4; ++gate) {
        const float* wr = W_hh + ((size_t)gate * HID + hidx) * HID + li * 32;
        #pragma unroll
        for (int k = 0; k < 32; k += 4) {
            const float4 w4 = *(const float4*)(wr + k);
            asm volatile("v_accvgpr_write_b32 %0, %1" : "=a"(wa[gate][k])     : "v"(w4.x));
            asm volatile("v_accvgpr_write_b32 %0, %1" : "=a"(wa[gate][k + 1]) : "v"(w4.y));
            asm volatile("v_accvgpr_write_b32 %0, %1" : "=a"(wa[gate][k + 2]) : "v"(w4.z));
            asm volatile("v_accvgpr_write_b32 %0, %1" : "=a"(wa[gate][k + 3]) : "v"(w4.w));
        }
    }

    const bool upd = (li == 0);
    float c = upd ? c0[hidx] : 0.0f;

    for (int s = 0; s < NSTEP; ++s) {
        // X_proj loads issued before the poll -> latency hidden under it.
        float xi = 0.f, xf = 0.f, xg = 0.f, xo = 0.f;
        if (upd) {
            const float* xpt = xp + (size_t)s * G4 + hidx;
            xi = xpt[0]; xf = xpt[HID]; xg = xpt[2 * HID]; xo = xpt[3 * HID];
        }

        // Poll own 8B slot of HSEQ[s] (both 4B halves flip independently).
        {
            const unsigned long long* slot =
                (const unsigned long long*)(hseq + (size_t)s * HID) + tid;
            unsigned long long hv = __hip_atomic_load(slot, __ATOMIC_RELAXED,
                                                      __HIP_MEMORY_SCOPE_AGENT);
            while ((unsigned)hv == SENTINEL || (unsigned)(hv >> 32) == SENTINEL) {
                __builtin_amdgcn_s_sleep(1);
                hv = __hip_atomic_load(slot, __ATOMIC_RELAXED,
                                       __HIP_MEMORY_SCOPE_AGENT);
            }
            const int i0 = 2 * tid;
            *(float2*)&h_lds[s & 1][i0 + ((i0 >> 5) << 2)] =
                make_float2(__uint_as_float((unsigned)hv),
                            __uint_as_float((unsigned)(hv >> 32)));
        }
        __syncthreads();   // fill -> compute (the only barrier per step)

        // k-outer / gate-inner dot: 8 b128 LDS reads, weights from AGPRs.
        float acc0 = 0.f, acc1 = 0.f, acc2 = 0.f, acc3 = 0.f;
        const float* hrow = &h_lds[s & 1][li * 36];
        #pragma unroll
        for (int k = 0; k < 32; k += 4) {
            const float4 h4 = *(const float4*)(hrow + k);
            float w0, w1, w2, w3;
            #define DOT_GATE(GATE, ACC)                                               \
                asm volatile("v_accvgpr_read_b32 %0, %1" : "=v"(w0) : "a"(wa[GATE][k]));     \
                asm volatile("v_accvgpr_read_b32 %0, %1" : "=v"(w1) : "a"(wa[GATE][k + 1])); \
                asm volatile("v_accvgpr_read_b32 %0, %1" : "=v"(w2) : "a"(wa[GATE][k + 2])); \
                asm volatile("v_accvgpr_read_b32 %0, %1" : "=v"(w3) : "a"(wa[GATE][k + 3])); \
                ACC = fmaf(w0, h4.x, ACC);                                            \
                ACC = fmaf(w1, h4.y, ACC);                                            \
                ACC = fmaf(w2, h4.z, ACC);                                            \
                ACC = fmaf(w3, h4.w, ACC);
            DOT_GATE(0, acc0)
            DOT_GATE(1, acc1)
            DOT_GATE(2, acc2)
            DOT_GATE(3, acc3)
            #undef DOT_GATE
        }
        float sums[4] = {acc0, acc1, acc2, acc3};
        #pragma unroll
        for (int gate = 0; gate < 4; ++gate) {
            float a = sums[gate];
            a += __shfl_xor(a, 1);
            a += __shfl_xor(a, 2);
            a += __shfl_xor(a, 4);
            a += __shfl_xor(a, 8);
            sums[gate] = a;
        }

        if (upd) {
            const float iv = fsig(sums[0] + xi);
            const float fv = fsig(sums[1] + xf);
            const float gv = ftanh(sums[2] + xg);
            const float ov = fsig(sums[3] + xo);
            c = fv * c + iv * gv;
            const float h = ov * ftanh(c);
            __hip_atomic_store((unsigned*)(hseq + (size_t)(s + 1) * HID + hidx),
                               __float_as_uint(h),
                               __ATOMIC_RELAXED, __HIP_MEMORY_SCOPE_AGENT);
            if (s == NSTEP - 1) {
                out[1 + hidx] = h;
                out[1 + HID + hidx] = c;
            }
        }
    }

    // Epilogue: WG 0 computes out[0] = sigmoid(fc_w . h_300 + fc_b).
    if (wg == 0) {
        const unsigned long long* slot =
            (const unsigned long long*)(hseq + (size_t)NSTEP * HID) + tid;
        unsigned long long hv = __hip_atomic_load(slot, __ATOMIC_RELAXED,
                                                  __HIP_MEMORY_SCOPE_AGENT);
        while ((unsigned)hv == SENTINEL || (unsigned)(hv >> 32) == SENTINEL) {
            __builtin_amdgcn_s_sleep(1);
            hv = __hip_atomic_load(slot, __ATOMIC_RELAXED,
                                   __HIP_MEMORY_SCOPE_AGENT);
        }
        red[tid] = __uint_as_float((unsigned)hv) * fc_w[2 * tid]
                 + __uint_as_float((unsigned)(hv >> 32)) * fc_w[2 * tid + 1];
        __syncthreads();
        for (int off = 128; off > 0; off >>= 1) {
            if (tid < off) red[tid] += red[tid + off];
            __syncthreads();
        }
        if (tid == 0) out[0] = fsig(red[0] + fc_b[0]);
    }
}

extern "C" void kernel_launch(void* const* d_in, const int* in_sizes, int n_in,
                              void* d_out, int out_size, void* d_ws, size_t ws_size,
                              hipStream_t stream) {
    (void)in_sizes; (void)n_in; (void)out_size; (void)ws_size;
    const int*   x     = (const int*)d_in[0];
    const float* h0    = (const float*)d_in[1];
    const float* c0    = (const float*)d_in[2];
    const float* emb   = (const float*)d_in[3];
    const float* W_ih  = (const float*)d_in[4];
    const float* W_hh  = (const float*)d_in[5];
    const float* b_ih  = (const float*)d_in[6];
    const float* b_hh  = (const float*)d_in[7];
    const float* fc_w  = (const float*)d_in[8];
    const float* fc_b  = (const float*)d_in[9];
    float* out = (float*)d_out;
    float* ws  = (float*)d_ws;

    xproj_init_kernel<<<dim3(NRG, NSG), dim3(TPB), 0, stream>>>(
        x, h0, emb, W_ih, b_ih, b_hh, ws);
    lstm_scan_kernel<<<dim3(NWG), dim3(TPB), 0, stream>>>(
        c0, W_hh, fc_w, fc_b, ws, out);
}